// Round 3
// baseline (405.806 us; speedup 1.0000x reference)
//
#include <hip/hip_runtime.h>
#include <hip/hip_fp16.h>
#include <cstdint>

// Problem constants (fixed by the reference)
#define NROWS 65536
#define DIM   512    // D
#define KDIM  256    // K
#define ODIM  512    // O
#define DEG   8
#define ZN    (NROWS * DIM)        // 33554432 z elements
#define TN    (DEG * KDIM * DIM)   // 1048576 T elements
#define CWN   (ODIM * KDIM)        // 131072 C_w elements

typedef _Float16 f16x8 __attribute__((ext_vector_type(8)));
typedef float    f32x4 __attribute__((ext_vector_type(4)));

// ---- helpers -------------------------------------------------------------

// async 16B global->LDS (global_load_lds_dwordx4). LDS dest is wave-uniform
// base + lane*16 by HW rule; all our slot mappings honor that.
__device__ __forceinline__ void gld_lds16(const void* g, void* l) {
  __builtin_amdgcn_global_load_lds(
      (const __attribute__((address_space(1))) unsigned int*)g,
      (__attribute__((address_space(3))) unsigned int*)l, 16, 0, 0);
}

__device__ __forceinline__ unsigned pack2h(float a, float b) {
  union { _Float16 h[2]; unsigned u; } x;
  x.h[0] = (_Float16)a; x.h[1] = (_Float16)b;
  return x.u;
}

// Swizzled byte offset in a tile of 64-half rows (128B = 8 x 16B chunks).
// chunk c of row r lives at slot (c+r)&7 -> conflict-free ds_read_b128.
__device__ __forceinline__ int swz(int row, int chunk) {
  return (row << 7) | (((chunk + row) & 7) << 4);
}

// ---- kernel 0: fp32->fp16 conversions (z, T with a_n folded, C_w) --------
// 8 elements/thread: two float4 loads, one 16B store.

__global__ void k_convert(const float* __restrict__ z,
                          const float* __restrict__ T,
                          const float* __restrict__ Cw,
                          _Float16* __restrict__ z16,
                          _Float16* __restrict__ Tb,
                          _Float16* __restrict__ Cwb) {
  long e = ((long)blockIdx.x * 256 + threadIdx.x) * 8;
  const float* src;
  _Float16* dst;
  float s = 1.0f;
  if (e < ZN) {
    src = z + e; dst = z16 + e;
  } else {
    long o = e - ZN;
    if (o < TN) {
      int n = (int)(o >> 17);  // / (KDIM*DIM); Tb[n] holds degree n+1
      s = (n == 0) ? 1.0f : (float)(2 * n + 1) / (float)(n + 1);
      src = T + o; dst = Tb + o;
    } else {
      long c = o - TN;
      if (c >= CWN) return;
      src = Cw + c; dst = Cwb + c;
    }
  }
  float4 v0 = *(const float4*)src;
  float4 v1 = *(const float4*)(src + 4);
  uint4 p;
  p.x = pack2h(v0.x * s, v0.y * s); p.y = pack2h(v0.z * s, v0.w * s);
  p.z = pack2h(v1.x * s, v1.y * s); p.w = pack2h(v1.z * s, v1.w * s);
  *(uint4*)dst = p;
}

// ---- kernel 1: fused GEMM + degree recurrence ----------------------------
// Block tile: 256 rows x 16 u-cols x 8 degrees. Wave covers 64 rows =
// 4 m-frags, so each B-fragment LDS read feeds 4 MFMAs (LDS-BW bound fix:
// bytes/FLOP (M+8)/(128M) = 0.023 at M=4 vs 0.039 at M=2).

__launch_bounds__(256, 2)
__global__ void k_poly(const _Float16* __restrict__ z16,
                       const float* __restrict__ T0,
                       const _Float16* __restrict__ Tb,
                       _Float16* __restrict__ u8) {
  __shared__ __align__(16) uint16_t As[256 * 64];  // 32 KB z tile
  __shared__ __align__(16) uint16_t Bs[128 * 64];  // 16 KB Tb tile (8deg x 16k)

  const int tid = threadIdx.x;
  const int wave = tid >> 6, lane = tid & 63;

  // grid 4096 = 256 row-tiles x 16 kg; kg-major so the 16 blocks sharing a
  // z-slice (256 KB) run near-simultaneously -> L2/L3 reuse.
  const int id = blockIdx.x;
  const int rt = id >> 4, kg = id & 15;
  const int r0 = rt << 8;
  const int k0 = kg << 4;

  const int m_l = lane & 15, kq = lane >> 4;
  const int wrow = wave << 6;                 // 64 rows per wave

  f32x4 acc[DEG][4];
#pragma unroll
  for (int n = 0; n < DEG; n++)
#pragma unroll
    for (int a = 0; a < 4; a++)
      acc[n][a] = (f32x4){0.f, 0.f, 0.f, 0.f};

  // Hoisted staging addresses. Slot lin, row=lin>>3, c=((lin&7)-row)&7
  // inverts the LDS swizzle on the global side.
  const _Float16* aptr[8];
  const _Float16* bptr[4];
  int lofsA[8], lofsB[4];
#pragma unroll
  for (int j = 0; j < 8; j++) {
    int lin = (j << 8) + tid;
    int row = lin >> 3;
    int c = ((lin & 7) - row) & 7;
    lofsA[j] = lin << 4;
    aptr[j] = z16 + (size_t)(r0 + row) * DIM + (c << 3);
  }
#pragma unroll
  for (int j = 0; j < 4; j++) {
    int lin = (j << 8) + tid;
    int row = lin >> 3;
    int c = ((lin & 7) - row) & 7;
    int n = row >> 4, kk = row & 15;
    lofsB[j] = lin << 4;
    bptr[j] = Tb + (size_t)((n << 8) + k0 + kk) * DIM + (c << 3);
  }

  for (int it = 0; it < DIM / 64; it++) {
    __syncthreads();  // previous iter's LDS reads done
#pragma unroll
    for (int j = 0; j < 8; j++) gld_lds16(aptr[j], (char*)As + lofsA[j]);
#pragma unroll
    for (int j = 0; j < 4; j++) gld_lds16(bptr[j], (char*)Bs + lofsB[j]);
#pragma unroll
    for (int j = 0; j < 8; j++) aptr[j] += 64;
#pragma unroll
    for (int j = 0; j < 4; j++) bptr[j] += 64;
    __syncthreads();  // drains async loads

#pragma unroll
    for (int ks = 0; ks < 2; ks++) {
      const int chunk = (ks << 2) + kq;
      f16x8 af[4];
#pragma unroll
      for (int mf = 0; mf < 4; mf++)
        af[mf] = *(const f16x8*)((char*)As + swz(wrow + (mf << 4) + m_l, chunk));
#pragma unroll
      for (int n = 0; n < DEG; n++) {
        f16x8 bv = *(const f16x8*)((char*)Bs + swz((n << 4) + m_l, chunk));
#pragma unroll
        for (int mf = 0; mf < 4; mf++)
          acc[n][mf] = __builtin_amdgcn_mfma_f32_16x16x32_f16(
              af[mf], bv, acc[n][mf], 0, 0, 0);
      }
    }
  }

  // Legendre recurrence per accumulator element, store u8 fp16.
  // C/D layout: col = lane&15, row = (lane>>4)*4 + reg  [m89-verified]
  const float bcoef[7] = {1.f/2.f, 2.f/3.f, 3.f/4.f, 4.f/5.f,
                          5.f/6.f, 6.f/7.f, 7.f/8.f};
  const int col = k0 + m_l;
  const float t0v = T0[col];
#pragma unroll
  for (int mf = 0; mf < 4; mf++) {
    f32x4 up2 = {t0v, t0v, t0v, t0v};
    f32x4 up1 = acc[0][mf];
#pragma unroll
    for (int n = 2; n <= DEG; n++) {
      f32x4 cur = acc[n - 1][mf] * up1 - bcoef[n - 2] * up2;
      up2 = up1; up1 = cur;
    }
    const int rbase = r0 + wrow + (mf << 4) + (kq << 2);
#pragma unroll
    for (int r = 0; r < 4; r++)
      u8[(size_t)(rbase + r) * KDIM + col] = (_Float16)up1[r];
  }
}

// ---- kernel 2: out[N,512] = u8[N,256] @ Cw^T + C_b (fp32 out) ------------
// Block tile 256 rows x 64 out-cols; wave covers 64 rows (4 m-frags).

__launch_bounds__(256, 3)
__global__ void k_out(const _Float16* __restrict__ u8,
                      const _Float16* __restrict__ Cwb,
                      const float* __restrict__ Cb,
                      float* __restrict__ out) {
  __shared__ __align__(16) uint16_t As[256 * 64];  // 32 KB u8 tile
  __shared__ __align__(16) uint16_t Bs[64 * 64];   //  8 KB Cw tile

  const int tid = threadIdx.x;
  const int wave = tid >> 6, lane = tid & 63;

  // grid 2048 = 256 row-tiles x 8 col-groups, cg-major for u8 L2 reuse
  const int id = blockIdx.x;
  const int rt = id >> 3, cg = id & 7;
  const int r0 = rt << 8;
  const int c0 = cg << 6;

  const int m_l = lane & 15, kq = lane >> 4;
  const int wrow = wave << 6;

  f32x4 acc[4][4];
#pragma unroll
  for (int a = 0; a < 4; a++)
#pragma unroll
    for (int b = 0; b < 4; b++)
      acc[a][b] = (f32x4){0.f, 0.f, 0.f, 0.f};

  const _Float16* aptr[8];
  const _Float16* bptr[2];
  int lofsA[8], lofsB[2];
#pragma unroll
  for (int j = 0; j < 8; j++) {
    int lin = (j << 8) + tid;
    int row = lin >> 3;
    int c = ((lin & 7) - row) & 7;
    lofsA[j] = lin << 4;
    aptr[j] = u8 + (size_t)(r0 + row) * KDIM + (c << 3);
  }
#pragma unroll
  for (int j = 0; j < 2; j++) {
    int lin = (j << 8) + tid;
    int row = lin >> 3;
    int c = ((lin & 7) - row) & 7;
    lofsB[j] = lin << 4;
    bptr[j] = Cwb + (size_t)(c0 + row) * KDIM + (c << 3);
  }

  for (int it = 0; it < KDIM / 64; it++) {
    __syncthreads();
#pragma unroll
    for (int j = 0; j < 8; j++) gld_lds16(aptr[j], (char*)As + lofsA[j]);
#pragma unroll
    for (int j = 0; j < 2; j++) gld_lds16(bptr[j], (char*)Bs + lofsB[j]);
#pragma unroll
    for (int j = 0; j < 8; j++) aptr[j] += 64;
#pragma unroll
    for (int j = 0; j < 2; j++) bptr[j] += 64;
    __syncthreads();

#pragma unroll
    for (int ks = 0; ks < 2; ks++) {
      const int chunk = (ks << 2) + kq;
      f16x8 af[4];
#pragma unroll
      for (int mf = 0; mf < 4; mf++)
        af[mf] = *(const f16x8*)((char*)As + swz(wrow + (mf << 4) + m_l, chunk));
#pragma unroll
      for (int kf = 0; kf < 4; kf++) {
        f16x8 bv = *(const f16x8*)((char*)Bs + swz((kf << 4) + m_l, chunk));
#pragma unroll
        for (int mf = 0; mf < 4; mf++)
          acc[mf][kf] = __builtin_amdgcn_mfma_f32_16x16x32_f16(
              af[mf], bv, acc[mf][kf], 0, 0, 0);
      }
    }
  }

#pragma unroll
  for (int kf = 0; kf < 4; kf++) {
    const int col = c0 + (kf << 4) + m_l;
    const float cb = Cb[col];
#pragma unroll
    for (int mf = 0; mf < 4; mf++) {
      const int rbase = r0 + wrow + (mf << 4) + (kq << 2);
#pragma unroll
      for (int r = 0; r < 4; r++)
        out[(size_t)(rbase + r) * ODIM + col] = acc[mf][kf][r] + cb;
    }
  }
}

// ---- launch --------------------------------------------------------------

extern "C" void kernel_launch(void* const* d_in, const int* in_sizes, int n_in,
                              void* d_out, int out_size, void* d_ws, size_t ws_size,
                              hipStream_t stream) {
  const float* z  = (const float*)d_in[0];
  const float* T0 = (const float*)d_in[1];
  const float* T  = (const float*)d_in[2];
  const float* Cw = (const float*)d_in[3];
  const float* Cb = (const float*)d_in[4];
  float* out = (float*)d_out;

  // ws layout: z16 64MB | Tb 2MB | Cwb 256KB | u8 32MB  (total ~98.25 MB)
  char* ws = (char*)d_ws;
  _Float16* z16 = (_Float16*)ws;
  _Float16* Tb  = (_Float16*)(ws + (size_t)ZN * 2);
  _Float16* Cwb = (_Float16*)(ws + (size_t)ZN * 2 + (size_t)TN * 2);
  _Float16* u8  = (_Float16*)(ws + (size_t)ZN * 2 + (size_t)TN * 2 + (size_t)CWN * 2);

  // (ZN+TN+CWN)/8/256 = 16960 blocks exactly
  k_convert<<<16960, 256, 0, stream>>>(z, T, Cw, z16, Tb, Cwb);
  k_poly<<<4096, 256, 0, stream>>>(z16, T0, Tb, u8);
  k_out<<<2048, 256, 0, stream>>>(u8, Cwb, Cb, out);
}

// Round 4
// 393.463 us; speedup vs baseline: 1.0314x; 1.0314x over previous
//
#include <hip/hip_runtime.h>
#include <hip/hip_fp16.h>
#include <cstdint>

// Problem constants (fixed by the reference)
#define NROWS 65536
#define DIM   512    // D
#define KDIM  256    // K
#define ODIM  512    // O
#define DEG   8
#define ZN    (NROWS * DIM)        // 33554432 z elements
#define TN    (DEG * KDIM * DIM)   // 1048576 T elements
#define CWN   (ODIM * KDIM)        // 131072 C_w elements

typedef _Float16 f16x8 __attribute__((ext_vector_type(8)));
typedef float    f32x4 __attribute__((ext_vector_type(4)));

// ---- helpers -------------------------------------------------------------

// async 16B global->LDS (global_load_lds_dwordx4). LDS dest is wave-uniform
// base + lane*16 by HW rule; all our slot mappings honor that.
__device__ __forceinline__ void gld_lds16(const void* g, void* l) {
  __builtin_amdgcn_global_load_lds(
      (const __attribute__((address_space(1))) unsigned int*)g,
      (__attribute__((address_space(3))) unsigned int*)l, 16, 0, 0);
}

__device__ __forceinline__ unsigned pack2h(float a, float b) {
  union { _Float16 h[2]; unsigned u; } x;
  x.h[0] = (_Float16)a; x.h[1] = (_Float16)b;
  return x.u;
}

// Swizzled byte offset in a tile of 64-half rows (128B = 8 x 16B chunks).
// chunk c of row r lives at slot (c+r)&7 -> conflict-free ds_read_b128.
__device__ __forceinline__ int swz(int row, int chunk) {
  return (row << 7) | (((chunk + row) & 7) << 4);
}

// ---- kernel 0: fp32->fp16 conversions (z, T with a_n folded, C_w) --------
// 8 elements/thread: two float4 loads, one 16B store.

__global__ void k_convert(const float* __restrict__ z,
                          const float* __restrict__ T,
                          const float* __restrict__ Cw,
                          _Float16* __restrict__ z16,
                          _Float16* __restrict__ Tb,
                          _Float16* __restrict__ Cwb) {
  long e = ((long)blockIdx.x * 256 + threadIdx.x) * 8;
  const float* src;
  _Float16* dst;
  float s = 1.0f;
  if (e < ZN) {
    src = z + e; dst = z16 + e;
  } else {
    long o = e - ZN;
    if (o < TN) {
      int n = (int)(o >> 17);  // / (KDIM*DIM); Tb[n] holds degree n+1
      s = (n == 0) ? 1.0f : (float)(2 * n + 1) / (float)(n + 1);
      src = T + o; dst = Tb + o;
    } else {
      long c = o - TN;
      if (c >= CWN) return;
      src = Cw + c; dst = Cwb + c;
    }
  }
  float4 v0 = *(const float4*)src;
  float4 v1 = *(const float4*)(src + 4);
  uint4 p;
  p.x = pack2h(v0.x * s, v0.y * s); p.y = pack2h(v0.z * s, v0.w * s);
  p.z = pack2h(v1.x * s, v1.y * s); p.w = pack2h(v1.z * s, v1.w * s);
  *(uint4*)dst = p;
}

// ---- kernel 1: fused GEMM + degree recurrence ----------------------------
// Block tile: 256 rows x 16 u-cols x 8 degrees; wave covers 64 rows
// (4 m-frags -> each B LDS read feeds 4 MFMAs).
// Grid swizzle: id = group*128 + kg*8 + (rt&7), so id%8 is CONSTANT across
// the 16 kg-blocks sharing one z-slice -> same XCD under round-robin
// block->XCD assignment -> z-slice fetched into one L2, not eight.
// (R3's kg-fastest mapping scattered them: FETCH 41->270 MB regression.)

__launch_bounds__(256, 2)
__global__ void k_poly(const _Float16* __restrict__ z16,
                       const float* __restrict__ T0,
                       const _Float16* __restrict__ Tb,
                       _Float16* __restrict__ u8) {
  __shared__ __align__(16) uint16_t As[256 * 64];  // 32 KB z tile
  __shared__ __align__(16) uint16_t Bs[128 * 64];  // 16 KB Tb tile (8deg x 16k)

  const int tid = threadIdx.x;
  const int wave = tid >> 6, lane = tid & 63;

  // decode: group=id>>7 (0..31), kg=(id>>3)&15, rt=group*8+(id&7)
  const int id = blockIdx.x;
  const int rt = ((id >> 7) << 3) | (id & 7);
  const int kg = (id >> 3) & 15;
  const int r0 = rt << 8;
  const int k0 = kg << 4;

  const int m_l = lane & 15, kq = lane >> 4;
  const int wrow = wave << 6;                 // 64 rows per wave

  f32x4 acc[DEG][4];
#pragma unroll
  for (int n = 0; n < DEG; n++)
#pragma unroll
    for (int a = 0; a < 4; a++)
      acc[n][a] = (f32x4){0.f, 0.f, 0.f, 0.f};

  // Hoisted staging addresses. Slot lin, row=lin>>3, c=((lin&7)-row)&7
  // inverts the LDS swizzle on the global side.
  const _Float16* aptr[8];
  const _Float16* bptr[4];
  int lofsA[8], lofsB[4];
#pragma unroll
  for (int j = 0; j < 8; j++) {
    int lin = (j << 8) + tid;
    int row = lin >> 3;
    int c = ((lin & 7) - row) & 7;
    lofsA[j] = lin << 4;
    aptr[j] = z16 + (size_t)(r0 + row) * DIM + (c << 3);
  }
#pragma unroll
  for (int j = 0; j < 4; j++) {
    int lin = (j << 8) + tid;
    int row = lin >> 3;
    int c = ((lin & 7) - row) & 7;
    int n = row >> 4, kk = row & 15;
    lofsB[j] = lin << 4;
    bptr[j] = Tb + (size_t)((n << 8) + k0 + kk) * DIM + (c << 3);
  }

  for (int it = 0; it < DIM / 64; it++) {
    __syncthreads();  // previous iter's LDS reads done
#pragma unroll
    for (int j = 0; j < 8; j++) gld_lds16(aptr[j], (char*)As + lofsA[j]);
#pragma unroll
    for (int j = 0; j < 4; j++) gld_lds16(bptr[j], (char*)Bs + lofsB[j]);
#pragma unroll
    for (int j = 0; j < 8; j++) aptr[j] += 64;
#pragma unroll
    for (int j = 0; j < 4; j++) bptr[j] += 64;
    __syncthreads();  // drains async loads

#pragma unroll
    for (int ks = 0; ks < 2; ks++) {
      const int chunk = (ks << 2) + kq;
      f16x8 af[4];
#pragma unroll
      for (int mf = 0; mf < 4; mf++)
        af[mf] = *(const f16x8*)((char*)As + swz(wrow + (mf << 4) + m_l, chunk));
#pragma unroll
      for (int n = 0; n < DEG; n++) {
        f16x8 bv = *(const f16x8*)((char*)Bs + swz((n << 4) + m_l, chunk));
#pragma unroll
        for (int mf = 0; mf < 4; mf++)
          acc[n][mf] = __builtin_amdgcn_mfma_f32_16x16x32_f16(
              af[mf], bv, acc[n][mf], 0, 0, 0);
      }
    }
  }

  // Legendre recurrence per accumulator element, store u8 fp16.
  // C/D layout: col = lane&15, row = (lane>>4)*4 + reg  [m89-verified]
  const float bcoef[7] = {1.f/2.f, 2.f/3.f, 3.f/4.f, 4.f/5.f,
                          5.f/6.f, 6.f/7.f, 7.f/8.f};
  const int col = k0 + m_l;
  const float t0v = T0[col];
#pragma unroll
  for (int mf = 0; mf < 4; mf++) {
    f32x4 up2 = {t0v, t0v, t0v, t0v};
    f32x4 up1 = acc[0][mf];
#pragma unroll
    for (int n = 2; n <= DEG; n++) {
      f32x4 cur = acc[n - 1][mf] * up1 - bcoef[n - 2] * up2;
      up2 = up1; up1 = cur;
    }
    const int rbase = r0 + wrow + (mf << 4) + (kq << 2);
#pragma unroll
    for (int r = 0; r < 4; r++)
      u8[(size_t)(rbase + r) * KDIM + col] = (_Float16)up1[r];
  }
}

// ---- kernel 2: out[N,512] = u8[N,256] @ Cw^T + C_b (fp32 out) ------------
// Block tile 256 rows x 64 out-cols. Same XCD swizzle (8 cg sharing a u8
// row-slice -> same XCD). Epilogue goes through LDS so global stores are
// fully-coalesced float4 (256B/16-lane segments).

__launch_bounds__(256, 3)
__global__ void k_out(const _Float16* __restrict__ u8,
                      const _Float16* __restrict__ Cwb,
                      const float* __restrict__ Cb,
                      float* __restrict__ out) {
  __shared__ __align__(16) uint16_t As[256 * 64];  // 32 KB u8 tile / f32 stage
  __shared__ __align__(16) uint16_t Bs[64 * 64];   //  8 KB Cw tile

  const int tid = threadIdx.x;
  const int wave = tid >> 6, lane = tid & 63;

  // decode: group=id>>6 (0..31), cg=(id>>3)&7, rt=group*8+(id&7)
  const int id = blockIdx.x;
  const int rt = ((id >> 6) << 3) | (id & 7);
  const int cg = (id >> 3) & 7;
  const int r0 = rt << 8;
  const int c0 = cg << 6;

  const int m_l = lane & 15, kq = lane >> 4;
  const int wrow = wave << 6;

  f32x4 acc[4][4];
#pragma unroll
  for (int a = 0; a < 4; a++)
#pragma unroll
    for (int b = 0; b < 4; b++)
      acc[a][b] = (f32x4){0.f, 0.f, 0.f, 0.f};

  const _Float16* aptr[8];
  const _Float16* bptr[2];
  int lofsA[8], lofsB[2];
#pragma unroll
  for (int j = 0; j < 8; j++) {
    int lin = (j << 8) + tid;
    int row = lin >> 3;
    int c = ((lin & 7) - row) & 7;
    lofsA[j] = lin << 4;
    aptr[j] = u8 + (size_t)(r0 + row) * KDIM + (c << 3);
  }
#pragma unroll
  for (int j = 0; j < 2; j++) {
    int lin = (j << 8) + tid;
    int row = lin >> 3;
    int c = ((lin & 7) - row) & 7;
    lofsB[j] = lin << 4;
    bptr[j] = Cwb + (size_t)(c0 + row) * KDIM + (c << 3);
  }

  for (int it = 0; it < KDIM / 64; it++) {
    __syncthreads();
#pragma unroll
    for (int j = 0; j < 8; j++) gld_lds16(aptr[j], (char*)As + lofsA[j]);
#pragma unroll
    for (int j = 0; j < 2; j++) gld_lds16(bptr[j], (char*)Bs + lofsB[j]);
#pragma unroll
    for (int j = 0; j < 8; j++) aptr[j] += 64;
#pragma unroll
    for (int j = 0; j < 2; j++) bptr[j] += 64;
    __syncthreads();

#pragma unroll
    for (int ks = 0; ks < 2; ks++) {
      const int chunk = (ks << 2) + kq;
      f16x8 af[4];
#pragma unroll
      for (int mf = 0; mf < 4; mf++)
        af[mf] = *(const f16x8*)((char*)As + swz(wrow + (mf << 4) + m_l, chunk));
#pragma unroll
      for (int kf = 0; kf < 4; kf++) {
        f16x8 bv = *(const f16x8*)((char*)Bs + swz((kf << 4) + m_l, chunk));
#pragma unroll
        for (int mf = 0; mf < 4; mf++)
          acc[mf][kf] = __builtin_amdgcn_mfma_f32_16x16x32_f16(
              af[mf], bv, acc[mf][kf], 0, 0, 0);
      }
    }
  }

  // Epilogue: acc -> LDS (f32, compact rows) -> coalesced float4 stores.
  // Compact row cr = wave*32 + mm*16 + kq*4 + r maps to block row
  // (cr>>5)*64 + half*32 + (cr&31).
  float* Ts = (float*)As;  // 128 x 64 f32 = 32 KB
  const int tcol = (tid & 15) << 2;
  const int trow = tid >> 4;
  const float4 cbv = *(const float4*)(Cb + c0 + tcol);
#pragma unroll
  for (int half = 0; half < 2; half++) {
    __syncthreads();
#pragma unroll
    for (int mm = 0; mm < 2; mm++) {
      const int mf = (half << 1) + mm;
      const int cr = (wave << 5) + (mm << 4) + (kq << 2);
#pragma unroll
      for (int kf = 0; kf < 4; kf++) {
        const int col = (kf << 4) + m_l;
#pragma unroll
        for (int r = 0; r < 4; r++)
          Ts[(cr + r) * 64 + col] = acc[mf][kf][r];
      }
    }
    __syncthreads();
#pragma unroll
    for (int p = 0; p < 8; p++) {
      const int cr = (p << 4) + trow;
      float4 v = *(const float4*)(Ts + cr * 64 + tcol);
      const int grow = ((cr >> 5) << 6) + (half << 5) + (cr & 31);
      float4 o;
      o.x = v.x + cbv.x; o.y = v.y + cbv.y;
      o.z = v.z + cbv.z; o.w = v.w + cbv.w;
      *(float4*)(out + (size_t)(r0 + grow) * ODIM + c0 + tcol) = o;
    }
  }
}

// ---- launch --------------------------------------------------------------

extern "C" void kernel_launch(void* const* d_in, const int* in_sizes, int n_in,
                              void* d_out, int out_size, void* d_ws, size_t ws_size,
                              hipStream_t stream) {
  const float* z  = (const float*)d_in[0];
  const float* T0 = (const float*)d_in[1];
  const float* T  = (const float*)d_in[2];
  const float* Cw = (const float*)d_in[3];
  const float* Cb = (const float*)d_in[4];
  float* out = (float*)d_out;

  // ws layout: z16 64MB | Tb 2MB | Cwb 256KB | u8 32MB  (total ~98.25 MB)
  char* ws = (char*)d_ws;
  _Float16* z16 = (_Float16*)ws;
  _Float16* Tb  = (_Float16*)(ws + (size_t)ZN * 2);
  _Float16* Cwb = (_Float16*)(ws + (size_t)ZN * 2 + (size_t)TN * 2);
  _Float16* u8  = (_Float16*)(ws + (size_t)ZN * 2 + (size_t)TN * 2 + (size_t)CWN * 2);

  // (ZN+TN+CWN)/8/256 = 16960 blocks exactly
  k_convert<<<16960, 256, 0, stream>>>(z, T, Cw, z16, Tb, Cwb);
  k_poly<<<4096, 256, 0, stream>>>(z16, T0, Tb, u8);
  k_out<<<2048, 256, 0, stream>>>(u8, Cwb, Cb, out);
}